// Round 7
// baseline (477.258 us; speedup 1.0000x reference)
//
#include <hip/hip_runtime.h>

// Sparsemax rows: x [16384,4096] fp32 -> out.
// PERSISTENT WAVES + REGISTER DOUBLE-BUFFER PIPELINE.
// Evidence trail: R3/R4 (barriers) 2.4-2.8 TB/s; R5 (HBM re-reads) bad;
// R6 (barrier-free) hit 3.4 TB/s but launch_bounds(256,5) caused ~174 MB
// scratch spill traffic. One-row-per-wave is latency-bound: ~900cyc load
// latency + ~2k cyc serial tau math paid in sequence, then the wave dies.
// Here each wave owns 5-6 rows (grid-stride): issue row i+1's 16 loads,
// compute tau + store row i while they fly, THEN pin/wait the prefetch.
// Per-row period -> max(HBM-share ~3.2k cyc, compute ~2k) = memory-bound.
// launch_bounds(256,3): cap ~170 VGPR, fits 128 data regs + overhead, NO
// spills. Zero LDS, zero barriers. Counts via ballot+popcount (scalar ALU).

constexpr int COLS = 4096;
constexpr int TPB  = 256;      // 4 waves/block
constexpr int WPB  = 4;
constexpr int GRID = 768;      // 3 blocks/CU -> 12 waves/CU persistent

using f32x4 = __attribute__((ext_vector_type(4))) float;

__device__ __forceinline__ float wred_sum(float v) {
    #pragma unroll
    for (int m = 32; m; m >>= 1) v += __shfl_xor(v, m, 64);
    return v;
}
__device__ __forceinline__ float wred_max(float v) {
    #pragma unroll
    for (int m = 32; m; m >>= 1) v = fmaxf(v, __shfl_xor(v, m, 64));
    return v;
}

__device__ __forceinline__ void load_row(const float* __restrict__ rowp, int lane,
                                         f32x4 (&q)[16]) {
    const f32x4* __restrict__ xr = reinterpret_cast<const f32x4*>(rowp);
    #pragma unroll
    for (int j = 0; j < 16; ++j) q[j] = xr[lane + 64 * j];
}
__device__ __forceinline__ void pin_row(f32x4 (&q)[16]) {
    #pragma unroll
    for (int j = 0; j < 16; ++j) asm volatile("" : "+v"(q[j]));
}

__device__ __forceinline__ void process_row(const f32x4 (&q)[16], int lane,
                                            float* __restrict__ outp) {
    // ---- row max ----
    float mx = -3.4e38f;
    #pragma unroll
    for (int j = 0; j < 16; ++j)
        mx = fmaxf(mx, fmaxf(fmaxf(q[j].x, q[j].y), fmaxf(q[j].z, q[j].w)));
    mx = wred_max(mx);
    const float lb = mx - 1.0f;  // tau* >= rowmax-1 -> support subset of {x > lb}

    // ---- extract candidates {x > lb} into 4 reg slots (quad-max gated) ----
    float c0 = lb, c1 = lb, c2 = lb, c3 = lb;   // lb sentinel never passes (> t >= lb)
    int k = 0;
    #pragma unroll
    for (int j = 0; j < 16; ++j) {
        float qm = fmaxf(fmaxf(q[j].x, q[j].y), fmaxf(q[j].z, q[j].w));
        if (qm > lb) {           // ~14/4096 elements qualify per row
            float e[4] = {q[j].x, q[j].y, q[j].z, q[j].w};
            #pragma unroll
            for (int t = 0; t < 4; ++t) {
                float xv = e[t];
                if (xv > lb) {
                    if      (k == 0) c0 = xv;
                    else if (k == 1) c1 = xv;
                    else if (k == 2) c2 = xv;
                    else if (k == 3) c3 = xv;
                    ++k;
                }
            }
        }
    }

    float tau;
    if (__ballot(k > 4) == 0ULL) {
        // ---- Michelot fixed point on slots; sums via butterfly, counts via
        // ballot+popcount (wave-uniform scalar) ----
        float s = ((c0 > lb) ? c0 : 0.f) + ((c1 > lb) ? c1 : 0.f)
                + ((c2 > lb) ? c2 : 0.f) + ((c3 > lb) ? c3 : 0.f);
        int n = __popcll(__ballot(c0 > lb)) + __popcll(__ballot(c1 > lb))
              + __popcll(__ballot(c2 > lb)) + __popcll(__ballot(c3 > lb));
        s = wred_sum(s);
        float t = (s - 1.f) / (float)n;          // t0 <= tau*, ascends to tau*
        for (int it = 0; it < 260; ++it) {       // active set strictly shrinks
            float si = ((c0 > t) ? c0 : 0.f) + ((c1 > t) ? c1 : 0.f)
                     + ((c2 > t) ? c2 : 0.f) + ((c3 > t) ? c3 : 0.f);
            int ci = __popcll(__ballot(c0 > t)) + __popcll(__ballot(c1 > t))
                   + __popcll(__ballot(c2 > t)) + __popcll(__ballot(c3 > t));
            si = wred_sum(si);                   // ci >= 1 (rowmax > tau*)
            float nt = (si - 1.f) / (float)ci;
            if (nt == t) break;                  // bit-identical across lanes
            t = nt;
        }
        tau = t;
    } else {
        // ---- pathological fallback: wave-local binary search over regs ----
        float lo = lb, hi = mx;
        for (int it = 0; it < 40; ++it) {
            float mid = 0.5f * (lo + hi);
            float s = 0.f;
            #pragma unroll
            for (int j = 0; j < 16; ++j)
                s += fmaxf(q[j].x - mid, 0.f) + fmaxf(q[j].y - mid, 0.f)
                   + fmaxf(q[j].z - mid, 0.f) + fmaxf(q[j].w - mid, 0.f);
            s = wred_sum(s);
            if (s > 1.f) lo = mid; else hi = mid;
        }
        float s = 0.f; int n = 0;
        #pragma unroll
        for (int j = 0; j < 16; ++j) {
            float e[4] = {q[j].x, q[j].y, q[j].z, q[j].w};
            #pragma unroll
            for (int t = 0; t < 4; ++t)
                if (e[t] > lo) { s += e[t]; n += 1; }
        }
        s = wred_sum(s);
        n = __popcll(__ballot(n > 0));  // dummy keep-alive; real count below
        // recompute count exactly (popcount per slot-pass not applicable here)
        float cf = 0.f;
        #pragma unroll
        for (int j = 0; j < 16; ++j) {
            float e[4] = {q[j].x, q[j].y, q[j].z, q[j].w};
            #pragma unroll
            for (int t = 0; t < 4; ++t) cf += (e[t] > lo) ? 1.f : 0.f;
        }
        cf = wred_sum(cf);
        tau = (s - 1.f) / cf;
    }

    // ---- epilogue: out = max(x - tau, 0), coalesced dwordx4 stores ----
    f32x4* __restrict__ orr = reinterpret_cast<f32x4*>(outp);
    #pragma unroll
    for (int j = 0; j < 16; ++j) {
        f32x4 r;
        r.x = fmaxf(q[j].x - tau, 0.f);
        r.y = fmaxf(q[j].y - tau, 0.f);
        r.z = fmaxf(q[j].z - tau, 0.f);
        r.w = fmaxf(q[j].w - tau, 0.f);
        orr[lane + 64 * j] = r;
    }
}

__global__ __launch_bounds__(TPB, 3) void sparsemax_kernel(const float* __restrict__ x,
                                                           float* __restrict__ out,
                                                           int rows) {
    const int lane   = threadIdx.x & 63;
    const int wid    = blockIdx.x * WPB + (threadIdx.x >> 6);
    const int stride = gridDim.x * WPB;

    f32x4 A[16], B[16];
    int r = wid;
    if (r >= rows) return;
    load_row(x + (size_t)r * COLS, lane, A);
    pin_row(A);
    for (;;) {
        int rn = r + stride;
        if (rn < rows) load_row(x + (size_t)rn * COLS, lane, B);  // prefetch in flight
        process_row(A, lane, out + (size_t)r * COLS);             // overlap compute
        if (rn >= rows) return;
        pin_row(B);                                               // wait prefetch here
        r = rn; rn = r + stride;
        if (rn < rows) load_row(x + (size_t)rn * COLS, lane, A);
        process_row(B, lane, out + (size_t)r * COLS);
        if (rn >= rows) return;
        pin_row(A);
        r = rn;
    }
}

extern "C" void kernel_launch(void* const* d_in, const int* in_sizes, int n_in,
                              void* d_out, int out_size, void* d_ws, size_t ws_size,
                              hipStream_t stream) {
    const float* x = (const float*)d_in[0];
    float*       o = (float*)d_out;
    const int rows = in_sizes[0] / COLS;   // 16384
    sparsemax_kernel<<<GRID, TPB, 0, stream>>>(x, o, rows);
}